// Round 8
// baseline (458.673 us; speedup 1.0000x reference)
//
#include <hip/hip_runtime.h>

#define D 128
#define GNUM 64
#define LNUM 4
#define BN_EPS 1e-5f
#define EPB 16384          // edges per hist/scatter block
#define SH_MAX 12544       // max NBIN*B the one-block scan supports

typedef short bf16x8 __attribute__((ext_vector_type(8)));       // 8 bf16 = 4 VGPR
typedef float f32x4 __attribute__((ext_vector_type(4)));
typedef unsigned short u16x8 __attribute__((ext_vector_type(8)));
typedef unsigned short u16x4 __attribute__((ext_vector_type(4)));

__device__ __forceinline__ float bf2f(unsigned short u) {
  union { unsigned int i; float f; } v; v.i = ((unsigned int)u) << 16; return v.f;
}
__device__ __forceinline__ unsigned short f2bf(float f) {
  union { float f; unsigned int i; } v; v.f = f;
  unsigned int b = v.i;
  return (unsigned short)((b + 0x7FFFu + ((b >> 16) & 1u)) >> 16);
}

// ---------------- CSR build: atomic-free binned counting sort ----------------
// bin = dst >> 8  (256 nodes per bin)

__global__ __launch_bounds__(256) void k_hist(const int* __restrict__ ei, int E,
                                              int B, int nbin, int* __restrict__ hist) {
  __shared__ int lh[256];
  int b = blockIdx.x, tx = threadIdx.x;
  lh[tx] = 0;
  __syncthreads();
  int s = b * EPB, e = min(s + EPB, E);
  for (int j = s + tx; j < e; j += 256) atomicAdd(&lh[ei[(size_t)E + j] >> 8], 1);
  __syncthreads();
  if (tx < nbin) hist[tx * B + b] = lh[tx];
}

__global__ __launch_bounds__(1024) void k_hscan(const int* __restrict__ hist, int M,
                                                int* __restrict__ off,
                                                int* __restrict__ rowptr, int N, int E) {
  __shared__ int sh[SH_MAX];
  __shared__ int sh2[1024];
  int tx = threadIdx.x;
  int chunk = (M + 1023) / 1024;
  for (int i = 0; i < chunk; ++i) {
    int idx = tx * chunk + i;
    sh[idx] = (idx < M) ? hist[idx] : 0;
  }
  __syncthreads();
  int s = 0;
  for (int i = 0; i < chunk; ++i) s += sh[tx * chunk + i];
  sh2[tx] = s;
  __syncthreads();
  for (int o = 1; o < 1024; o <<= 1) {
    int u = (tx >= o) ? sh2[tx - o] : 0;
    __syncthreads();
    sh2[tx] += u;
    __syncthreads();
  }
  int run = (tx == 0) ? 0 : sh2[tx - 1];
  for (int i = 0; i < chunk; ++i) {
    int idx = tx * chunk + i;
    if (idx < M) { int v = sh[idx]; off[idx] = run; run += v; }
  }
  if (tx == 0) rowptr[N] = E;
}

__global__ __launch_bounds__(256) void k_scatter(const int* __restrict__ ei, int E,
                                                 int B, int nbin,
                                                 const int* __restrict__ off,
                                                 int2* __restrict__ sorted) {
  __shared__ int cur[256];
  int b = blockIdx.x, tx = threadIdx.x;
  if (tx < nbin) cur[tx] = off[tx * B + b];
  __syncthreads();
  int s = b * EPB, e = min(s + EPB, E);
  for (int j = s + tx; j < e; j += 256) {
    int d = ei[(size_t)E + j];
    int sc = ei[j];
    int p = atomicAdd(&cur[d >> 8], 1);
    sorted[p] = make_int2(d, sc);
  }
}

__global__ __launch_bounds__(256) void k_build(const int2* __restrict__ sorted,
                                               const int* __restrict__ off,
                                               int B, int nbin, int E, int N,
                                               int* __restrict__ rowptr,
                                               int* __restrict__ col) {
  __shared__ int cnt[256], excl[256], cur[256];
  int beta = blockIdx.x, tx = threadIdx.x;
  int s = off[beta * B];
  int e = (beta + 1 < nbin) ? off[(beta + 1) * B] : E;
  cnt[tx] = 0;
  __syncthreads();
  for (int j = s + tx; j < e; j += 256) atomicAdd(&cnt[sorted[j].x & 255], 1);
  __syncthreads();
  int v = cnt[tx];
  excl[tx] = v;
  __syncthreads();
  for (int o = 1; o < 256; o <<= 1) {
    int u = (tx >= o) ? excl[tx - o] : 0;
    __syncthreads();
    excl[tx] += u;
    __syncthreads();
  }
  int ex = excl[tx] - v;
  int n = beta * 256 + tx;
  if (n < N) rowptr[n] = s + ex;
  cur[tx] = s + ex;
  __syncthreads();
  for (int j = s + tx; j < e; j += 256) {
    int2 p = sorted[j];
    int q = atomicAdd(&cur[p.x & 255], 1);
    col[q] = p.y;
  }
}

// graph boundaries via binary search on sorted batch
__global__ void k_bounds(const int* __restrict__ batch, int N, int* __restrict__ bound) {
  int g = threadIdx.x;
  if (g > GNUM) return;
  int lo = 0, hi = N;
  while (lo < hi) { int mid = (lo + hi) >> 1; if (batch[mid] < g) lo = mid + 1; else hi = mid; }
  bound[g] = lo;
}

// ---------------- prep: fp32 -> bf16 ----------------
__global__ void k_prep_x(const float* __restrict__ x, unsigned short* __restrict__ hx, int total4) {
  int i = blockIdx.x * 256 + threadIdx.x;
  if (i < total4) {
    f32x4 v = ((const f32x4*)x)[i];
    u16x4 o; o[0] = f2bf(v[0]); o[1] = f2bf(v[1]); o[2] = f2bf(v[2]); o[3] = f2bf(v[3]);
    ((u16x4*)hx)[i] = o;
  }
}

__global__ __launch_bounds__(256) void k_prep_w(const float* __restrict__ W1,
                                                const float* __restrict__ W2,
                                                unsigned short* __restrict__ wt) {
  int l = blockIdx.x;
  const float* W = (l < LNUM) ? (W1 + (size_t)l * D * D) : (W2 + (size_t)(l - LNUM) * D * D);
  unsigned short* o = wt + (size_t)l * D * D;
#pragma unroll
  for (int i = 0; i < 64; ++i) {
    int idx = threadIdx.x + 256 * i;       // idx = k*128 + n
    int k = idx >> 7, n = idx & 127;
    o[n * D + k] = f2bf(W[idx]);
  }
}

// ---------------- aggregation: z = h + mean_nbr(h), bf16 ----------------
// One wave per node; 4 groups of 16 lanes each process a different edge,
// each lane loads 16B of the 256B row; unroll x4 -> up to 16 rows in flight
// (one full average-degree node per latency round trip).
__global__ __launch_bounds__(256) void k_aggz(const unsigned short* __restrict__ hin,
                                              const int* __restrict__ rowptr,
                                              const int* __restrict__ col,
                                              int N, unsigned short* __restrict__ z) {
  int tx = threadIdx.x;
  int w = tx >> 6, l = tx & 63;
  int g = l >> 4;             // edge subgroup 0..3
  int c = l & 15;             // 16B slice of the row
  int n = blockIdx.x * 4 + w;
  if (n >= N) return;
  int e0 = rowptr[n], e1 = rowptr[n + 1];
  const u16x8* h8 = (const u16x8*)hin;   // one row = 16 x u16x8
  f32x4 a0 = {0.f, 0.f, 0.f, 0.f}, a1 = {0.f, 0.f, 0.f, 0.f};
  f32x4 b0 = {0.f, 0.f, 0.f, 0.f}, b1 = {0.f, 0.f, 0.f, 0.f};
  f32x4 c0 = {0.f, 0.f, 0.f, 0.f}, c1 = {0.f, 0.f, 0.f, 0.f};
  f32x4 d0 = {0.f, 0.f, 0.f, 0.f}, d1 = {0.f, 0.f, 0.f, 0.f};
  int j = e0 + g;
  for (; j + 12 < e1; j += 16) {
    int cj0 = col[j];
    int cj1 = col[j + 4];
    int cj2 = col[j + 8];
    int cj3 = col[j + 12];
    u16x8 v0 = h8[(size_t)cj0 * 16 + c];
    u16x8 v1 = h8[(size_t)cj1 * 16 + c];
    u16x8 v2 = h8[(size_t)cj2 * 16 + c];
    u16x8 v3 = h8[(size_t)cj3 * 16 + c];
    a0[0] += bf2f(v0[0]); a0[1] += bf2f(v0[1]); a0[2] += bf2f(v0[2]); a0[3] += bf2f(v0[3]);
    a1[0] += bf2f(v0[4]); a1[1] += bf2f(v0[5]); a1[2] += bf2f(v0[6]); a1[3] += bf2f(v0[7]);
    b0[0] += bf2f(v1[0]); b0[1] += bf2f(v1[1]); b0[2] += bf2f(v1[2]); b0[3] += bf2f(v1[3]);
    b1[0] += bf2f(v1[4]); b1[1] += bf2f(v1[5]); b1[2] += bf2f(v1[6]); b1[3] += bf2f(v1[7]);
    c0[0] += bf2f(v2[0]); c0[1] += bf2f(v2[1]); c0[2] += bf2f(v2[2]); c0[3] += bf2f(v2[3]);
    c1[0] += bf2f(v2[4]); c1[1] += bf2f(v2[5]); c1[2] += bf2f(v2[6]); c1[3] += bf2f(v2[7]);
    d0[0] += bf2f(v3[0]); d0[1] += bf2f(v3[1]); d0[2] += bf2f(v3[2]); d0[3] += bf2f(v3[3]);
    d1[0] += bf2f(v3[4]); d1[1] += bf2f(v3[5]); d1[2] += bf2f(v3[6]); d1[3] += bf2f(v3[7]);
  }
  for (; j < e1; j += 4) {
    int cj = col[j];
    u16x8 v = h8[(size_t)cj * 16 + c];
    a0[0] += bf2f(v[0]); a0[1] += bf2f(v[1]); a0[2] += bf2f(v[2]); a0[3] += bf2f(v[3]);
    a1[0] += bf2f(v[4]); a1[1] += bf2f(v[5]); a1[2] += bf2f(v[6]); a1[3] += bf2f(v[7]);
  }
  a0 += b0; c0 += d0; a0 += c0;
  a1 += b1; c1 += d1; a1 += c1;
#pragma unroll
  for (int m = 16; m <= 32; m <<= 1) {
#pragma unroll
    for (int i = 0; i < 4; ++i) {
      a0[i] += __shfl_xor(a0[i], m, 64);
      a1[i] += __shfl_xor(a1[i], m, 64);
    }
  }
  if (g == 0) {
    float inv = (e1 > e0) ? 1.f / (float)(e1 - e0) : 0.f;
    u16x8 hv = h8[(size_t)n * 16 + c];
    u16x8 o;
    o[0] = f2bf(bf2f(hv[0]) + a0[0] * inv);
    o[1] = f2bf(bf2f(hv[1]) + a0[1] * inv);
    o[2] = f2bf(bf2f(hv[2]) + a0[2] * inv);
    o[3] = f2bf(bf2f(hv[3]) + a0[3] * inv);
    o[4] = f2bf(bf2f(hv[4]) + a1[0] * inv);
    o[5] = f2bf(bf2f(hv[5]) + a1[1] * inv);
    o[6] = f2bf(bf2f(hv[6]) + a1[2] * inv);
    o[7] = f2bf(bf2f(hv[7]) + a1[3] * inv);
    ((u16x8*)z)[(size_t)n * 16 + c] = o;
  }
}

// ---------------- GEMM1: t = z @ W1 + b1 (bf16 MFMA), + BN partials ----------------
__global__ __launch_bounds__(256) void k_gemm1(const unsigned short* __restrict__ z,
                                               const unsigned short* __restrict__ wt,
                                               const float* __restrict__ bias,
                                               unsigned short* __restrict__ t,
                                               float* __restrict__ partials, int N) {
  __shared__ union { unsigned short zt[64 * D]; float red[2 * 8 * D]; } uA;  // 16KB/8KB
  __shared__ union { unsigned short wl[D * D]; float out[64 * D]; } uB;      // 32KB
  int tx = threadIdx.x;
  int r0 = blockIdx.x * 64;
  const u16x8* zg = (const u16x8*)(z + (size_t)r0 * D);
#pragma unroll
  for (int i = 0; i < 4; ++i) {
    int cid = tx + 256 * i;
    int row = cid >> 4, c16 = cid & 15;
    u16x8 v = zg[cid];
    *(u16x8*)((char*)uA.zt + row * 256 + ((c16 * 16) ^ ((row & 7) << 4))) = v;
  }
  const u16x8* wg = (const u16x8*)wt;
#pragma unroll
  for (int i = 0; i < 8; ++i) {
    int cid = tx + 256 * i;
    int row = cid >> 4, c16 = cid & 15;
    u16x8 v = wg[cid];
    *(u16x8*)((char*)uB.wl + row * 256 + ((c16 * 16) ^ ((row & 7) << 4))) = v;
  }
  __syncthreads();
  int l = tx & 63, w = tx >> 6;
  int lm = l & 15, lg = l >> 4;
  f32x4 acc[8];
#pragma unroll
  for (int c = 0; c < 8; ++c) { float bv = bias[c * 16 + lm]; acc[c] = (f32x4){bv, bv, bv, bv}; }
  int arow = 16 * w + lm;
  const char* zb = (const char*)uA.zt + arow * 256;
  int aswz = (arow & 7) << 4;
#pragma unroll
  for (int kt = 0; kt < 4; ++kt) {
    int koff = kt * 64 + lg * 16;
    bf16x8 af = *(const bf16x8*)(zb + (koff ^ aswz));
#pragma unroll
    for (int c = 0; c < 8; ++c) {
      int n = c * 16 + lm;
      bf16x8 bfr = *(const bf16x8*)((const char*)uB.wl + n * 256 + (koff ^ ((n & 7) << 4)));
      acc[c] = __builtin_amdgcn_mfma_f32_16x16x32_bf16(af, bfr, acc[c], 0, 0, 0);
    }
  }
  __syncthreads();  // wl free -> out
#pragma unroll
  for (int c = 0; c < 8; ++c)
#pragma unroll
    for (int r = 0; r < 4; ++r)
      uB.out[(16 * w + 4 * lg + r) * D + c * 16 + lm] = acc[c][r];
  __syncthreads();
  int tc = tx & 31, tr = tx >> 5;
  f32x4 s = {0.f, 0.f, 0.f, 0.f}, q = {0.f, 0.f, 0.f, 0.f};
#pragma unroll
  for (int i = 0; i < 8; ++i) {
    int row = i * 8 + tr;
    f32x4 v = *(f32x4*)&uB.out[row * D + tc * 4];
    u16x4 o; o[0] = f2bf(v[0]); o[1] = f2bf(v[1]); o[2] = f2bf(v[2]); o[3] = f2bf(v[3]);
    *(u16x4*)(t + (size_t)(r0 + row) * D + tc * 4) = o;   // t is padded
    if (r0 + row < N) { s += v; q += v * v; }
  }
  *(f32x4*)&uA.red[tr * D + tc * 4] = s;
  *(f32x4*)&uA.red[8 * D + tr * D + tc * 4] = q;
  __syncthreads();
  int colx = tx & 127, which = tx >> 7;
  float S = 0.f;
#pragma unroll
  for (int j = 0; j < 8; ++j) S += uA.red[which * 8 * D + j * D + colx];
  partials[(size_t)blockIdx.x * 256 + tx] = S;
}

// reduce stage 1: 64 blocks stride over gemm1 blocks -> partial2[64][256]
__global__ __launch_bounds__(256) void k_red1(const float* __restrict__ partials, int NB,
                                              float* __restrict__ partial2) {
  int tx = threadIdx.x;
  float S = 0.f;
  for (int b = blockIdx.x; b < NB; b += 64) S += partials[(size_t)b * 256 + tx];
  partial2[(size_t)blockIdx.x * 256 + tx] = S;
}

// reduce stage 2 -> stats[0..127]=gamma*rstd, stats[128..255]=beta-mu*gamma*rstd
__global__ __launch_bounds__(256) void k_finalize(const float* __restrict__ partial2,
                                                  const float* __restrict__ gamma,
                                                  const float* __restrict__ beta,
                                                  float* __restrict__ stats, int N) {
  __shared__ float sh[256];
  int tx = threadIdx.x;
  float S = 0.f;
#pragma unroll 8
  for (int b = 0; b < 64; ++b) S += partial2[(size_t)b * 256 + tx];
  sh[tx] = S;
  __syncthreads();
  if (tx < D) {
    float mu = sh[tx] / (float)N;
    float var = sh[D + tx] / (float)N - mu * mu;
    float rstd = rsqrtf(fmaxf(var, 0.f) + BN_EPS);
    float A = gamma[tx] * rstd;
    stats[tx] = A;
    stats[D + tx] = beta[tx] - mu * A;
  }
}

// ---------------- GEMM2: h_l = relu(bn(t)) @ W2 + b2 (write-only, no pool RMW) ----------------
__global__ __launch_bounds__(256) void k_gemm2(const unsigned short* __restrict__ t,
                                               const unsigned short* __restrict__ wt,
                                               const float* __restrict__ bias,
                                               const float* __restrict__ stats,
                                               unsigned short* __restrict__ h, int N) {
  __shared__ unsigned short at[64 * D];                                      // 16KB
  __shared__ union { unsigned short wl[D * D]; float out[64 * D]; } uB;      // 32KB
  int tx = threadIdx.x;
  int r0 = blockIdx.x * 64;
  const u16x8* tg = (const u16x8*)(t + (size_t)r0 * D);
#pragma unroll
  for (int i = 0; i < 4; ++i) {
    int cid = tx + 256 * i;
    int row = cid >> 4, c16 = cid & 15;
    u16x8 v = tg[cid];
    int c0 = c16 * 8;
    f32x4 a0 = *(const f32x4*)&stats[c0];
    f32x4 a1 = *(const f32x4*)&stats[c0 + 4];
    f32x4 b0 = *(const f32x4*)&stats[D + c0];
    f32x4 b1v = *(const f32x4*)&stats[D + c0 + 4];
    u16x8 o;
    o[0] = f2bf(fmaxf(bf2f(v[0]) * a0[0] + b0[0], 0.f));
    o[1] = f2bf(fmaxf(bf2f(v[1]) * a0[1] + b0[1], 0.f));
    o[2] = f2bf(fmaxf(bf2f(v[2]) * a0[2] + b0[2], 0.f));
    o[3] = f2bf(fmaxf(bf2f(v[3]) * a0[3] + b0[3], 0.f));
    o[4] = f2bf(fmaxf(bf2f(v[4]) * a1[0] + b1v[0], 0.f));
    o[5] = f2bf(fmaxf(bf2f(v[5]) * a1[1] + b1v[1], 0.f));
    o[6] = f2bf(fmaxf(bf2f(v[6]) * a1[2] + b1v[2], 0.f));
    o[7] = f2bf(fmaxf(bf2f(v[7]) * a1[3] + b1v[3], 0.f));
    *(u16x8*)((char*)at + row * 256 + ((c16 * 16) ^ ((row & 7) << 4))) = o;
  }
  const u16x8* wg = (const u16x8*)wt;
#pragma unroll
  for (int i = 0; i < 8; ++i) {
    int cid = tx + 256 * i;
    int row = cid >> 4, c16 = cid & 15;
    u16x8 v = wg[cid];
    *(u16x8*)((char*)uB.wl + row * 256 + ((c16 * 16) ^ ((row & 7) << 4))) = v;
  }
  __syncthreads();
  int l = tx & 63, w = tx >> 6;
  int lm = l & 15, lg = l >> 4;
  f32x4 acc[8];
#pragma unroll
  for (int c = 0; c < 8; ++c) { float bv = bias[c * 16 + lm]; acc[c] = (f32x4){bv, bv, bv, bv}; }
  int arow = 16 * w + lm;
  const char* ab = (const char*)at + arow * 256;
  int aswz = (arow & 7) << 4;
#pragma unroll
  for (int kt = 0; kt < 4; ++kt) {
    int koff = kt * 64 + lg * 16;
    bf16x8 af = *(const bf16x8*)(ab + (koff ^ aswz));
#pragma unroll
    for (int c = 0; c < 8; ++c) {
      int n = c * 16 + lm;
      bf16x8 bfr = *(const bf16x8*)((const char*)uB.wl + n * 256 + (koff ^ ((n & 7) << 4)));
      acc[c] = __builtin_amdgcn_mfma_f32_16x16x32_bf16(af, bfr, acc[c], 0, 0, 0);
    }
  }
  __syncthreads();
#pragma unroll
  for (int c = 0; c < 8; ++c)
#pragma unroll
    for (int r = 0; r < 4; ++r)
      uB.out[(16 * w + 4 * lg + r) * D + c * 16 + lm] = acc[c][r];
  __syncthreads();
  int tc = tx & 31, tr = tx >> 5;
#pragma unroll
  for (int i = 0; i < 8; ++i) {
    int row = i * 8 + tr;
    int gr = r0 + row;
    if (gr < N) {
      f32x4 v = *(f32x4*)&uB.out[row * D + tc * 4];
      u16x4 hb; hb[0] = f2bf(v[0]); hb[1] = f2bf(v[1]); hb[2] = f2bf(v[2]); hb[3] = f2bf(v[3]);
      *(u16x4*)(h + (size_t)gr * D + tc * 4) = hb;
    }
  }
}

// ---------------- node_pool = sum of the 4 layer outputs ----------------
__global__ void k_npool(const unsigned short* __restrict__ h0,
                        const unsigned short* __restrict__ h1,
                        const unsigned short* __restrict__ h2,
                        const unsigned short* __restrict__ h3,
                        float* __restrict__ np, int total8) {
  int i = blockIdx.x * 256 + threadIdx.x;
  if (i >= total8) return;
  u16x8 a = ((const u16x8*)h0)[i];
  u16x8 b = ((const u16x8*)h1)[i];
  u16x8 c = ((const u16x8*)h2)[i];
  u16x8 d = ((const u16x8*)h3)[i];
  f32x4 lo, hi;
#pragma unroll
  for (int j = 0; j < 4; ++j) {
    lo[j] = (bf2f(a[j]) + bf2f(b[j])) + (bf2f(c[j]) + bf2f(d[j]));
    hi[j] = (bf2f(a[4 + j]) + bf2f(b[4 + j])) + (bf2f(c[4 + j]) + bf2f(d[4 + j]));
  }
  ((f32x4*)np)[2 * i] = lo;
  ((f32x4*)np)[2 * i + 1] = hi;
}

// ---------------- pooling: g_pool[g] = mean over rows of node_pool ----------------
__global__ __launch_bounds__(256) void k_gpool(const float* __restrict__ np,
                                               const int* __restrict__ bound,
                                               float* __restrict__ gp) {
  __shared__ float red[8 * D];
  int g = blockIdx.x;
  int s = bound[g], e = bound[g + 1];
  int tc = threadIdx.x & 31, tr = threadIdx.x >> 5;
  f32x4 a = {0.f, 0.f, 0.f, 0.f};
  for (int r = s + tr; r < e; r += 8)
    a += *(const f32x4*)(np + (size_t)r * D + tc * 4);
  *(f32x4*)&red[tr * D + tc * 4] = a;
  __syncthreads();
  if (threadIdx.x < D) {
    float v = 0.f;
#pragma unroll
    for (int j = 0; j < 8; ++j) v += red[j * D + threadIdx.x];
    float c = (float)(e - s);
    gp[(size_t)g * D + threadIdx.x] = v / fmaxf(c, 1.f);
  }
}

// ---------------- launch ----------------
extern "C" void kernel_launch(void* const* d_in, const int* in_sizes, int n_in,
                              void* d_out, int out_size, void* d_ws,
                              size_t ws_size, hipStream_t stream) {
  const float* x = (const float*)d_in[0];
  const int* ei = (const int*)d_in[1];
  const int* batch = (const int*)d_in[2];
  const float* W1 = (const float*)d_in[3];
  const float* b1 = (const float*)d_in[4];
  const float* gamma = (const float*)d_in[5];
  const float* beta = (const float*)d_in[6];
  const float* W2 = (const float*)d_in[7];
  const float* b2 = (const float*)d_in[8];
  int N = in_sizes[0] / D;
  int E = in_sizes[1] / 2;
  int Npad = (N + 63) & ~63;
  int gb = Npad / 64;
  int B = (E + EPB - 1) / EPB;       // hist/scatter blocks (49 for E=800k)
  int nbin = (N + 255) / 256;        // 196 for N=50k
  int M = nbin * B;                  // 9604 <= SH_MAX

  float* out = (float*)d_out;
  float* node_pool = out;
  float* g_pool = out + (size_t)N * D;

  char* wp = (char*)d_ws;
  unsigned short* t_hx = (unsigned short*)wp; wp += (size_t)Npad * D * 2;  // t, aliased x-bf16
  unsigned short* z = (unsigned short*)wp;    wp += (size_t)Npad * D * 2;
  unsigned short* hbuf[LNUM];
  for (int l = 0; l < LNUM; ++l) { hbuf[l] = (unsigned short*)wp; wp += (size_t)Npad * D * 2; }
  unsigned short* wt = (unsigned short*)wp;   wp += (size_t)8 * D * D * 2;
  float* partials = (float*)wp;               wp += (size_t)gb * 256 * 4;
  float* partial2 = (float*)wp;               wp += (size_t)64 * 256 * 4;
  float* stats = (float*)wp;                  wp += (size_t)2 * D * 4;
  int* bound = (int*)wp;                      wp += (size_t)(GNUM + 4) * 4;
  int* rowptr = (int*)wp;                     wp += (size_t)(N + 1) * 4;
  int* hist = (int*)wp;                       wp += (size_t)SH_MAX * 4;
  int* off = (int*)wp;                        wp += (size_t)SH_MAX * 4;
  int* col = (int*)wp;                        wp += (size_t)E * 4;
  int2* sorted = (int2*)wp;                   wp += (size_t)E * 8;

  if (Npad > N) {  // pad hygiene: gemm1 stages z pad rows; keep them defined
    hipMemsetAsync(z + (size_t)N * D, 0, (size_t)(Npad - N) * D * 2, stream);
  }

  k_prep_w<<<8, 256, 0, stream>>>(W1, W2, wt);
  k_prep_x<<<(N * 32 + 255) / 256, 256, 0, stream>>>(x, t_hx, N * 32);
  k_hist<<<B, 256, 0, stream>>>(ei, E, B, nbin, hist);
  k_hscan<<<1, 1024, 0, stream>>>(hist, M, off, rowptr, N, E);
  k_scatter<<<B, 256, 0, stream>>>(ei, E, B, nbin, off, sorted);
  k_build<<<nbin, 256, 0, stream>>>(sorted, off, B, nbin, E, N, rowptr, col);
  k_bounds<<<1, 128, 0, stream>>>(batch, N, bound);

  int ab = (N + 3) / 4;
  for (int ll = 0; ll < LNUM; ++ll) {
    const unsigned short* hin = (ll == 0) ? t_hx : hbuf[ll - 1];
    k_aggz<<<ab, 256, 0, stream>>>(hin, rowptr, col, N, z);
    k_gemm1<<<gb, 256, 0, stream>>>(z, wt + (size_t)ll * D * D, b1 + (size_t)ll * D,
                                    t_hx, partials, N);
    k_red1<<<64, 256, 0, stream>>>(partials, gb, partial2);
    k_finalize<<<1, 256, 0, stream>>>(partial2, gamma + (size_t)ll * D,
                                      beta + (size_t)ll * D, stats, N);
    k_gemm2<<<gb, 256, 0, stream>>>(t_hx, wt + (size_t)(LNUM + ll) * D * D,
                                    b2 + (size_t)ll * D, stats, hbuf[ll], N);
  }
  int total8 = N * (D / 8);
  k_npool<<<(total8 + 255) / 256, 256, 0, stream>>>(hbuf[0], hbuf[1], hbuf[2], hbuf[3],
                                                    node_pool, total8);
  k_gpool<<<GNUM, 256, 0, stream>>>(node_pool, bound, g_pool);
}